// Round 1
// baseline (232.153 us; speedup 1.0000x reference)
//
#include <hip/hip_runtime.h>
#include <math.h>

#define R_ROUTES 1152
#define CIN 8
#define COUT 16
#define BATCH 512
#define NCAPS 10
#define NUM_ROUNDS 3

// One workgroup per (n, b) pair. Priors (1152 x 16 fp32 = 72 KB) live in LDS.
// LDS total ~79.5 KB -> 2 blocks/CU (158.9 KB of 160 KB).
extern "C" __global__ void __launch_bounds__(256, 2)
capsule_routing(const float* __restrict__ x,
                const float* __restrict__ W,
                float* __restrict__ out)
{
    __shared__ float p[R_ROUTES * COUT];   // 73728 B: priors, row-major [r][o]
    __shared__ float ew[R_ROUTES];         // 4608 B: exp(logit - max) per route
    __shared__ float partial[256];         // 1024 B: per-(o,g) partial sums
    __shared__ float sv[COUT];             // 64 B: s vector
    __shared__ float sred[8];              // 32 B: cross-wave reduce scratch

    const int blk = blockIdx.x;            // n-major: blk = n*512 + b  (L2 locality for W[n])
    const int n = blk >> 9;
    const int b = blk & 511;
    const int t = threadIdx.x;

    const float* __restrict__ xb = x + (size_t)b * (R_ROUTES * CIN);
    const float* __restrict__ Wn = W + (size_t)n * (R_ROUTES * CIN * COUT);

    // ---------------- Phase A: priors[r][o] = sum_i x[b][r][i] * W[n][r][i][o]
    // thread -> (row-sub = t>>2, o-quad = t&3); 64 rows/iter, 18 iters.
    {
        const int oq = t & 3;
        const int rsub = t >> 2;
        #pragma unroll 2
        for (int it = 0; it < 18; ++it) {
            const int r = it * 64 + rsub;
            const float4* wrow = (const float4*)(Wn + (size_t)r * (CIN * COUT) + oq * 4);
            const float4 xv0 = *(const float4*)(xb + r * CIN);
            const float4 xv1 = *(const float4*)(xb + r * CIN + 4);
            const float xs[8] = {xv0.x, xv0.y, xv0.z, xv0.w, xv1.x, xv1.y, xv1.z, xv1.w};
            float ax = 0.f, ay = 0.f, az = 0.f, aw = 0.f;
            #pragma unroll
            for (int i = 0; i < 8; ++i) {
                const float4 wv = wrow[i * 4];   // stride COUT floats between i
                ax = fmaf(xs[i], wv.x, ax);
                ay = fmaf(xs[i], wv.y, ay);
                az = fmaf(xs[i], wv.z, az);
                aw = fmaf(xs[i], wv.w, aw);
            }
            float4 res; res.x = ax; res.y = ay; res.z = az; res.w = aw;
            *(float4*)(p + r * COUT + oq * 4) = res;
        }
    }
    __syncthreads();

    // ---------------- Phase B: 3 routing rounds, all in LDS/registers
    float bl[5];
    #pragma unroll
    for (int k = 0; k < 5; ++k) bl[k] = 0.f;
    const int nr = (t < 128) ? 5 : 4;      // rows r = t + 256k, k < nr (covers 1152)

    const int g = t >> 4;                  // 0..15
    const int o = t & 15;                  // 0..15

    for (int round = 0; round < NUM_ROUNDS; ++round) {
        float invZ;
        if (round == 0) {
            // softmax of zeros -> uniform
            for (int k = 0; k < nr; ++k) ew[t + (k << 8)] = 1.0f;
            invZ = 1.0f / (float)R_ROUTES;
            __syncthreads();
        } else {
            // block max of logits
            float m = -INFINITY;
            for (int k = 0; k < nr; ++k) m = fmaxf(m, bl[k]);
            #pragma unroll
            for (int off = 32; off > 0; off >>= 1) m = fmaxf(m, __shfl_down(m, off, 64));
            if ((t & 63) == 0) sred[t >> 6] = m;
            __syncthreads();
            m = fmaxf(fmaxf(sred[0], sred[1]), fmaxf(sred[2], sred[3]));
            __syncthreads();
            // exp + block sum
            float lsum = 0.f;
            for (int k = 0; k < nr; ++k) {
                const float e = __expf(bl[k] - m);
                ew[t + (k << 8)] = e;
                lsum += e;
            }
            #pragma unroll
            for (int off = 32; off > 0; off >>= 1) lsum += __shfl_down(lsum, off, 64);
            if ((t & 63) == 0) sred[t >> 6] = lsum;
            __syncthreads();
            const float Z = sred[0] + sred[1] + sred[2] + sred[3];
            invZ = 1.0f / Z;
            __syncthreads();   // protect sred + ensure ew visible before reads below
        }

        // s_o = invZ * sum_r ew[r] * p[r][o] : thread (g,o), rows r = rr*16+g
        {
            float acc = 0.f;
            #pragma unroll 8
            for (int rr = 0; rr < 72; ++rr) {
                const int r = (rr << 4) + g;
                acc = fmaf(ew[r], p[(r << 4) + o], acc);
            }
            partial[(o << 4) + g] = acc;
        }
        __syncthreads();
        if (t < 16) {
            float acc = 0.f;
            #pragma unroll
            for (int gg = 0; gg < 16; ++gg) acc += partial[(t << 4) + gg];
            sv[t] = acc * invZ;
        }
        __syncthreads();

        // squash factor (computed redundantly by all threads; cheap broadcasts)
        float snorm = 0.f;
        #pragma unroll
        for (int oo = 0; oo < 16; ++oo) { const float s = sv[oo]; snorm = fmaf(s, s, snorm); }
        const float factor = snorm / ((1.0f + snorm) * sqrtf(snorm));

        if (round == NUM_ROUNDS - 1) {
            if (t < 16) out[(size_t)blk * COUT + t] = factor * sv[t];
        } else {
            // logit update: b_r += factor * dot(p[r][:], s[:])
            for (int k = 0; k < nr; ++k) {
                const int r = t + (k << 8);
                const float* pr = p + (r << 4);
                float d = 0.f;
                #pragma unroll
                for (int oo = 0; oo < 16; ++oo) {
                    const int oi = (oo + o) & 15;   // stagger: 4-way instead of 32-way conflicts
                    d = fmaf(pr[oi], sv[oi], d);
                }
                bl[k] += factor * d;
            }
            __syncthreads();
        }
    }
}

extern "C" void kernel_launch(void* const* d_in, const int* in_sizes, int n_in,
                              void* d_out, int out_size, void* d_ws, size_t ws_size,
                              hipStream_t stream) {
    const float* x = (const float*)d_in[0];   // [512, 1152, 8] fp32
    const float* W = (const float*)d_in[1];   // [10, 1152, 8, 16] fp32
    float* out = (float*)d_out;               // [10, 512, 1, 1, 16] fp32

    dim3 grid(NCAPS * BATCH);                 // 5120 blocks, n-major
    dim3 block(256);
    capsule_routing<<<grid, block, 0, stream>>>(x, W, out);
}